// Round 1
// baseline (184.986 us; speedup 1.0000x reference)
//
#include <hip/hip_runtime.h>
#include <hip/hip_bf16.h>

// GAT x2 (3 heads, E=2048, batch 0 only) + 2-layer GCN, log_softmax / leaky.
// Non-neighbor exp(-30) terms dropped (~1e-10 effect vs threshold 32).
// adj -> 512 KB bitmask; all E x E passes consume bits. No atomics (f32
// atomicAdd = uncached 16B HBM RMW, ~45us/1M, R6). Split-K via plain-stored
// partials merged inline in consumers. NO cooperative grid.sync (~30us each
// on 8-XCD MI355X, R11). 7 dispatches.
// R12: k3 rebuilt LDS-free. Old k3 was LDS-return-BW bound (~288 cyc/ii/CU
// from wave-uniform broadcast ds_read_b128). New k3: i-side operands
// distributed 1-ii-per-lane + __builtin_amdgcn_readlane broadcast; masks as
// per-lane registers from a transposed bitmask bmT (built by k2's spare
// waves via ballot). h*(1/rowsum) hoisted into k2 (hsS).

// ---------------------------------------------------------------------------
// K01: blocks 0..511: bitmask (4 rows each). blocks 512..559: features.
__global__ __launch_bounds__(256) void k01(
    const float* __restrict__ adj0, unsigned int* __restrict__ bm,
    const float* __restrict__ node, const float* __restrict__ uv,
    const float* __restrict__ Wt1, const float* __restrict__ at1,
    const float* __restrict__ Wt2, const float* __restrict__ at2,
    float* __restrict__ hcol, float* __restrict__ pack1, float* __restrict__ pack2) {
  int b = blockIdx.x;
  if (b < 512) {
    int lane = threadIdx.x & 63, w = threadIdx.x >> 6;
    int row = b * 4 + w;
    const float* arow = adj0 + (size_t)row * 2048;
#pragma unroll 4
    for (int it = 0; it < 32; ++it) {
      float v = arow[it * 64 + lane];
      unsigned long long mask = __ballot(v == 1.0f);
      if (lane == 0) bm[row * 64 + it * 2] = (unsigned int)mask;
      else if (lane == 32) bm[row * 64 + it * 2 + 1] = (unsigned int)(mask >> 32);
    }
    return;
  }
  __shared__ float sW[192];
  __shared__ float sA[12];
  int fb = b - 512;                 // 0..47
  int g = fb / 24;
  int h = (fb / 8) % 3;
  int e = (fb % 8) * 256 + threadIdx.x;
  const float* W = (g ? Wt2 : Wt1) + h * 192;
  const float* A = (g ? at2 : at1) + h * 12;
  const float* x = (g ? uv : node) + e * 32;
  if (threadIdx.x < 192) sW[threadIdx.x] = W[threadIdx.x];
  if (threadIdx.x < 12) sA[threadIdx.x] = A[threadIdx.x];
  __syncthreads();
  float xv[32];
#pragma unroll
  for (int i = 0; i < 32; ++i) xv[i] = x[i];
  float hv[6];
#pragma unroll
  for (int d = 0; d < 6; ++d) hv[d] = 0.f;
#pragma unroll
  for (int i = 0; i < 32; ++i)
#pragma unroll
    for (int d = 0; d < 6; ++d) hv[d] += xv[i] * sW[i * 6 + d];
  float e1 = 0.f, e2 = 0.f;
#pragma unroll
  for (int d = 0; d < 6; ++d) {
    e1 += hv[d] * sA[d];
    e2 += hv[d] * sA[6 + d];
  }
  int c = g * 3 + h;
#pragma unroll
  for (int d = 0; d < 6; ++d) hcol[(c * 6 + d) * 2048 + e] = hv[d];
  pack1[c * 2048 + e] = e1;
  pack1[(6 + c) * 2048 + e] = __expf(e1);
  pack1[(12 + c) * 2048 + e] = __expf(0.2f * e1);
  pack2[c * 2048 + e] = e2;
  pack2[(6 + c) * 2048 + e] = __expf(e2);
  pack2[(12 + c) * 2048 + e] = __expf(0.2f * e2);
}

// ---------------------------------------------------------------------------
// K2: rowsum -> hsS[c*6+d][i] = h[i,d] / rowsum(i,c). Block 384 (wave = comp
// c), 8 rows per block, lanes sweep j 4-at-a-time. Waves 0..3 additionally
// build one 64x64 transposed-bitmask tile each (bmT for k3).
__global__ __launch_bounds__(384) void k2_rowsum(
    const unsigned int* __restrict__ bm, const float* __restrict__ pack1,
    const float* __restrict__ pack2, const float* __restrict__ hcol,
    unsigned int* __restrict__ bmT, float* __restrict__ hsS) {
  int tid = threadIdx.x;
  int c = tid >> 6, lane = tid & 63;
  // --- bmT side job: tile t = blockIdx.x*4 + c (1024 tiles total) ---
  if (c < 4) {
    int t = blockIdx.x * 4 + c;
    int ti = t >> 5, tj = t & 31;    // ti: 64-row block, tj: 64-col block
    const unsigned int* rw = &bm[(size_t)(ti * 64 + lane) * 64 + tj * 2];
    unsigned int rlo = rw[0], rhi = rw[1];
    unsigned long long rowbits = ((unsigned long long)rhi << 32) | rlo;
    unsigned int myLo = 0, myHi = 0;
#pragma unroll
    for (int jb = 0; jb < 64; ++jb) {
      unsigned long long colm = __ballot((unsigned int)((rowbits >> jb) & 1ull));
      if (jb == lane) { myLo = (unsigned int)colm; myHi = (unsigned int)(colm >> 32); }
    }
    *(uint2*)&bmT[(size_t)(tj * 64 + lane) * 64 + ti * 2] = make_uint2(myLo, myHi);
  }
  // --- rowsum ---
  int i0 = blockIdx.x * 8;
  const float4* p2_4 = (const float4*)pack2;
  float e1r[8], p1r[8], q1r[8], sum[8];
#pragma unroll
  for (int r = 0; r < 8; ++r) {
    e1r[r] = pack1[c * 2048 + i0 + r];
    p1r[r] = pack1[(6 + c) * 2048 + i0 + r];
    q1r[r] = pack1[(12 + c) * 2048 + i0 + r];
    sum[r] = 0.f;
  }
  int sh = (lane & 7) * 4;
#pragma unroll
  for (int it = 0; it < 8; ++it) {
    int j4 = it * 64 + lane;  // float4 index; covers j = 4*j4 .. +3
    float4 e2 = p2_4[c * 512 + j4];
    float4 p2 = p2_4[(6 + c) * 512 + j4];
    float4 q2 = p2_4[(12 + c) * 512 + j4];
    int wbase = it * 8 + (lane >> 3);
    float abx, aby, abz, abw;
#pragma unroll
    for (int r = 0; r < 8; ++r) {
      unsigned int wd = bm[(i0 + r) * 64 + wbase] >> sh;
      { float e = e1r[r] + e2.x; bool p = e > 0.f;
        abx = (p ? p1r[r] : q1r[r]) * (p ? p2.x : q2.x); }
      { float e = e1r[r] + e2.y; bool p = e > 0.f;
        aby = (p ? p1r[r] : q1r[r]) * (p ? p2.y : q2.y); }
      { float e = e1r[r] + e2.z; bool p = e > 0.f;
        abz = (p ? p1r[r] : q1r[r]) * (p ? p2.z : q2.z); }
      { float e = e1r[r] + e2.w; bool p = e > 0.f;
        abw = (p ? p1r[r] : q1r[r]) * (p ? p2.w : q2.w); }
      float s = ((wd & 1u) ? abx : 0.f) + ((wd & 2u) ? aby : 0.f) +
                ((wd & 4u) ? abz : 0.f) + ((wd & 8u) ? abw : 0.f);
      sum[r] += s;
    }
  }
  // full-lane butterfly so every lane has all 8 sums
#pragma unroll
  for (int r = 0; r < 8; ++r) {
#pragma unroll
    for (int off = 32; off > 0; off >>= 1) sum[r] += __shfl_xor(sum[r], off);
  }
  if (lane < 6) {
    int row = c * 6 + lane;
#pragma unroll
    for (int r = 0; r < 8; ++r) {
      float inv = 1.0f / sum[r];
      hsS[row * 2048 + i0 + r] = hcol[row * 2048 + i0 + r] * inv;
    }
  }
}

// ---------------------------------------------------------------------------
// K3: hp_part[s][k][j] = sum_{i in split s} w(i,j,c) * hsS[c*6+d][i].
// LDS-free: i-side operands distributed 1-per-lane, broadcast via readlane;
// column mask bits per-lane from bmT. Wave = comp c; 4 j per lane (j-tile
// 256); i-split 64. Grid (8 j-tiles, 32 i-splits).
#define RLF(x, l) __int_as_float(__builtin_amdgcn_readlane(__float_as_int(x), (l)))
__global__ __launch_bounds__(384) void k3_hprime(
    const unsigned int* __restrict__ bmT, const float* __restrict__ pack1,
    const float* __restrict__ pack2, const float* __restrict__ hsS,
    float* __restrict__ hp_part) {
  int tid = threadIdx.x;
  int c = tid >> 6, jl = tid & 63;
  int j0 = blockIdx.x * 256;
  int i0 = blockIdx.y * 64;
  int il = i0 + jl;
  // per-lane i-side record (lane L holds values for i = i0+L)
  float e1L = pack1[c * 2048 + il];
  float p1L = pack1[(6 + c) * 2048 + il];
  float q1L = pack1[(12 + c) * 2048 + il];
  float hsL0 = hsS[(c * 6 + 0) * 2048 + il];
  float hsL1 = hsS[(c * 6 + 1) * 2048 + il];
  float hsL2 = hsS[(c * 6 + 2) * 2048 + il];
  float hsL3 = hsS[(c * 6 + 3) * 2048 + il];
  float hsL4 = hsS[(c * 6 + 4) * 2048 + il];
  float hsL5 = hsS[(c * 6 + 5) * 2048 + il];
  // per-lane column mask bits: for each j-group g, 64 bits over i0..i0+63
  unsigned int cw0[4], cw1[4];
#pragma unroll
  for (int g = 0; g < 4; ++g) {
    uint2 w = *(const uint2*)&bmT[(size_t)(j0 + g * 64 + jl) * 64 + (i0 >> 5)];
    cw0[g] = w.x; cw1[g] = w.y;
  }
  // per-lane j-side
  float e2v[4], p2v[4], q2v[4];
#pragma unroll
  for (int g = 0; g < 4; ++g) {
    int j = j0 + g * 64 + jl;
    e2v[g] = pack2[c * 2048 + j];
    p2v[g] = pack2[(6 + c) * 2048 + j];
    q2v[g] = pack2[(12 + c) * 2048 + j];
  }
  float acc[4][6];
#pragma unroll
  for (int g = 0; g < 4; ++g)
#pragma unroll
    for (int d = 0; d < 6; ++d) acc[g][d] = 0.f;

#pragma unroll
  for (int half = 0; half < 2; ++half) {
#pragma unroll 8
    for (int i2 = 0; i2 < 32; ++i2) {
      int ii = half * 32 + i2;
      float e1 = RLF(e1L, ii);
      float p1 = RLF(p1L, ii);
      float q1 = RLF(q1L, ii);
      float h0 = RLF(hsL0, ii), h1 = RLF(hsL1, ii), h2 = RLF(hsL2, ii);
      float h3 = RLF(hsL3, ii), h4 = RLF(hsL4, ii), h5 = RLF(hsL5, ii);
#pragma unroll
      for (int g = 0; g < 4; ++g) {
        float e = e1 + e2v[g];
        bool pos = e > 0.f;
        float abp = p1 * p2v[g];
        float abq = q1 * q2v[g];
        float ab = pos ? abp : abq;
        unsigned int bit = ((half ? cw1[g] : cw0[g]) >> i2) & 1u;
        float wgt = bit ? ab : 0.f;
        acc[g][0] += wgt * h0; acc[g][1] += wgt * h1; acc[g][2] += wgt * h2;
        acc[g][3] += wgt * h3; acc[g][4] += wgt * h4; acc[g][5] += wgt * h5;
      }
    }
  }
  float* hp = hp_part + (size_t)blockIdx.y * 73728;
#pragma unroll
  for (int g = 0; g < 4; ++g) {
    int j = j0 + g * 64 + jl;
#pragma unroll
    for (int d = 0; d < 6; ++d) hp[(c * 6 + d) * 2048 + j] = acc[g][d];
  }
}

// ---------------------------------------------------------------------------
// K4: merge 32 hp partials -> elu -> T[j][32] = {hcY@Wg1, hcO@Wo1}.
// 16 j per block, grid 128.
__global__ __launch_bounds__(256) void k4_T(
    const float* __restrict__ hp_part, const float* __restrict__ Wg1,
    const float* __restrict__ Wo1, float* __restrict__ T) {
  __shared__ float sHP[16 * 37];
  __shared__ float sWg[288], sWo[288];
  int tid = threadIdx.x;
  int j0 = blockIdx.x * 16;
  for (int idx = tid; idx < 288; idx += 256) {
    sWg[idx] = Wg1[idx];
    sWo[idx] = Wo1[idx];
  }
  for (int idx = tid; idx < 576; idx += 256) {
    int r = idx >> 4, jl = idx & 15;
    float s = 0.f;
#pragma unroll
    for (int sp = 0; sp < 32; ++sp)
      s += hp_part[(size_t)sp * 73728 + r * 2048 + j0 + jl];
    sHP[jl * 37 + r] = s;
  }
  __syncthreads();
  int jl = tid & 15, wq = tid >> 4;  // 16 slots: gat(2) x colpair(8)
  int gat = wq >> 3;
  int c0 = (wq & 7) * 2;
  const float* Wp = gat ? sWo : sWg;
  float a0 = 0.f, a1 = 0.f;
#pragma unroll
  for (int r = 0; r < 18; ++r) {
    float x = sHP[jl * 37 + gat * 18 + r];
    float hc = x > 0.f ? x : __expf(x) - 1.f;
    a0 += hc * Wp[r * 16 + c0];
    a1 += hc * Wp[r * 16 + c0 + 1];
  }
  T[(j0 + jl) * 32 + gat * 16 + c0] = a0;
  T[(j0 + jl) * 32 + gat * 16 + c0 + 1] = a1;
}

// ---------------------------------------------------------------------------
// K5: Craw_part[s][r][c] = sum_{k in split s} bit(r,k) * T[k][c].
// Grid (32 row-tiles of 64, 16 k-splits of 128). Plain float4 stores.
__global__ __launch_bounds__(256) void k5_gcn1(
    const unsigned int* __restrict__ bm, const float* __restrict__ T,
    float* __restrict__ Craw_part) {
  __shared__ unsigned int sM[64 * 4];
  __shared__ float4 sT4[128 * 8];
  const float4* T4 = (const float4*)T;
  int tid = threadIdx.x;
  int rl = tid & 31, cg = tid >> 5;
  int i0 = blockIdx.x * 64;
  int k0 = blockIdx.y * 128;
  sM[tid] = bm[(size_t)(i0 + (tid >> 2)) * 64 + (k0 >> 5) + (tid & 3)];
  for (int idx = tid; idx < 1024; idx += 256) sT4[idx] = T4[k0 * 8 + idx];
  __syncthreads();
  float a0x = 0.f, a0y = 0.f, a0z = 0.f, a0w = 0.f;
  float a1x = 0.f, a1y = 0.f, a1z = 0.f, a1w = 0.f;
#pragma unroll
  for (int wi = 0; wi < 4; ++wi) {
    unsigned int wA = sM[rl * 4 + wi];
    unsigned int wB = sM[(rl + 32) * 4 + wi];
#pragma unroll 16
    for (int kb = 0; kb < 32; ++kb) {
      float4 t = sT4[(wi * 32 + kb) * 8 + cg];
      float mA = (float)((wA >> kb) & 1u);
      float mB = (float)((wB >> kb) & 1u);
      a0x += mA * t.x; a0y += mA * t.y; a0z += mA * t.z; a0w += mA * t.w;
      a1x += mB * t.x; a1y += mB * t.y; a1z += mB * t.z; a1w += mB * t.w;
    }
  }
  float* base = Craw_part + (size_t)blockIdx.y * 65536;
  *(float4*)&base[(i0 + rl) * 32 + cg * 4] = make_float4(a0x, a0y, a0z, a0w);
  *(float4*)&base[(i0 + rl + 32) * 32 + cg * 4] = make_float4(a1x, a1y, a1z, a1w);
}

// ---------------------------------------------------------------------------
// K6: merge 16 Craw partials, +bias, relu, @Wg2/@Wo2 -> T2[j][4]. Grid 256.
__global__ __launch_bounds__(256) void k6_T2(
    const float* __restrict__ Craw_part, const float* __restrict__ bg1,
    const float* __restrict__ Wg2, const float* __restrict__ bo1,
    const float* __restrict__ Wo2, float* __restrict__ T2) {
  int tid = threadIdx.x;
  int wave = tid >> 6, lane = tid & 63;
  int j = blockIdx.x * 8 + wave * 2 + (lane >> 5);
  int cl = lane & 31;
  int gat = cl >> 4, cc = cl & 15;
  float x = 0.f;
#pragma unroll
  for (int sp = 0; sp < 16; ++sp) x += Craw_part[(size_t)sp * 65536 + j * 32 + cl];
  x += gat ? bo1[cc] : bg1[cc];
  x = x > 0.f ? x : 0.f;
  float wa = gat ? Wo2[cc * 2 + 0] : Wg2[cc * 2 + 0];
  float wb = gat ? Wo2[cc * 2 + 1] : Wg2[cc * 2 + 1];
  float pa = x * wa, pb = x * wb;
#pragma unroll
  for (int m = 8; m > 0; m >>= 1) {
    pa += __shfl_xor(pa, m);
    pb += __shfl_xor(pb, m);
  }
  if (cc == 0) {
    T2[j * 4 + gat * 2 + 0] = pa;
    T2[j * 4 + gat * 2 + 1] = pb;
  }
}

// ---------------------------------------------------------------------------
// K7: final out = a0 @ T2 (+bias), log_softmax(axis=1) + leaky(0.01).
// Wave per row, grid 512.
__global__ __launch_bounds__(256) void k7_final(
    const unsigned int* __restrict__ bm, const float* __restrict__ T2,
    const float* __restrict__ bg2, const float* __restrict__ bo2,
    float* __restrict__ out) {
  int tid = threadIdx.x;
  int lane = tid & 63, w = tid >> 6;
  int r = blockIdx.x * 4 + w;
  const float4* T24 = (const float4*)T2;
  float4 acc = make_float4(0.f, 0.f, 0.f, 0.f);
  int sh = lane & 31;
#pragma unroll 8
  for (int it = 0; it < 32; ++it) {
    int k = it * 64 + lane;
    unsigned int wd = bm[r * 64 + it * 2 + (lane >> 5)];
    float m = (float)((wd >> sh) & 1u);
    float4 t = T24[k];
    acc.x += m * t.x;
    acc.y += m * t.y;
    acc.z += m * t.z;
    acc.w += m * t.w;
  }
#pragma unroll
  for (int off = 32; off > 0; off >>= 1) {
    acc.x += __shfl_down(acc.x, off);
    acc.y += __shfl_down(acc.y, off);
    acc.z += __shfl_down(acc.z, off);
    acc.w += __shfl_down(acc.w, off);
  }
  if (lane == 0) {
    float y0 = acc.x + bg2[0], y1 = acc.y + bg2[1];
    float m = fmaxf(y0, y1);
    float ls = m + logf(__expf(y0 - m) + __expf(y1 - m));
    out[r * 2 + 0] = y0 - ls;
    out[r * 2 + 1] = y1 - ls;
    float o0 = acc.z + bo2[0], o1 = acc.w + bo2[1];
    out[4096 + r * 2 + 0] = o0 > 0.f ? o0 : 0.01f * o0;
    out[4096 + r * 2 + 1] = o1 > 0.f ? o1 : 0.01f * o1;
  }
}

extern "C" void kernel_launch(void* const* d_in, const int* in_sizes, int n_in,
                              void* d_out, int out_size, void* d_ws, size_t ws_size,
                              hipStream_t stream) {
  const float* node = (const float*)d_in[0];
  const float* uv = (const float*)d_in[1];
  const float* adj = (const float*)d_in[2];  // batch 0 = first 2048*2048
  const float* Wt1 = (const float*)d_in[3];
  const float* at1 = (const float*)d_in[4];
  const float* Wt2 = (const float*)d_in[5];
  const float* at2 = (const float*)d_in[6];
  const float* Wg1 = (const float*)d_in[7];
  const float* bg1 = (const float*)d_in[8];
  const float* Wg2 = (const float*)d_in[9];
  const float* bg2 = (const float*)d_in[10];
  const float* Wo1 = (const float*)d_in[11];
  const float* bo1 = (const float*)d_in[12];
  const float* Wo2 = (const float*)d_in[13];
  const float* bo2 = (const float*)d_in[14];
  float* ws = (float*)d_ws;
  float* hcol = ws;                               // 73728
  float* pack1 = ws + 73728;                      // 36864
  float* pack2 = ws + 110592;                     // 36864
  float* hsS = ws + 147456;                       // 73728
  float* T = ws + 221184;                         // 65536
  float* T2 = ws + 286720;                        // 8192
  unsigned int* bm = (unsigned int*)(ws + 294912);   // 131072 u32 = 512 KB
  unsigned int* bmT = (unsigned int*)(ws + 425984);  // 131072 u32 = 512 KB
  float* hp_part = ws + 557056;                   // 32 * 73728 = 2359296
  float* Craw_part = ws + 2916352;                // 16 * 65536 = 1048576
  float* out = (float*)d_out;

  k01<<<560, 256, 0, stream>>>(adj, bm, node, uv, Wt1, at1, Wt2, at2,
                               hcol, pack1, pack2);
  k2_rowsum<<<256, 384, 0, stream>>>(bm, pack1, pack2, hcol, bmT, hsS);
  k3_hprime<<<dim3(8, 32), 384, 0, stream>>>(bmT, pack1, pack2, hsS, hp_part);
  k4_T<<<128, 256, 0, stream>>>(hp_part, Wg1, Wo1, T);
  k5_gcn1<<<dim3(32, 16), 256, 0, stream>>>(bm, T, Craw_part);
  k6_T2<<<256, 256, 0, stream>>>(Craw_part, bg1, Wg2, bo1, Wo2, T2);
  k7_final<<<512, 256, 0, stream>>>(bm, T2, bg2, bo2, out);
}

// Round 2
// 170.710 us; speedup vs baseline: 1.0836x; 1.0836x over previous
//
#include <hip/hip_runtime.h>
#include <hip/hip_bf16.h>

// GAT x2 (3 heads, E=2048, batch 0 only) + 2-layer GCN, log_softmax / leaky.
// Non-neighbor exp(-30) terms dropped (~1e-10 effect vs threshold 32).
// R12 post-mortem: kernel-internal optimizations are neutral -> time is
// dominated by dispatch serialization + fixed overhead, not inner loops.
// R13: 7 -> 5 dispatches, partials eliminated:
//   kA: adj -> bm AND bmT in one pass (per-tile ballots) + features.
//   kB: rowsums -> hsS (= h * 1/rowsum).
//   kC: k3+k4 fused: full-i sweep per j-tile -> hp final in-block -> elu
//       -> x Wg1/Wo1 -> T. No hp_part.
//   kD: k5+k6 fused: full-k sweep per 8-row tile, T read from L2 (no LDS
//       staging), -> relu+bias -> x W2 -> T2. No Craw_part.
//   kE: final A*T2 + log_softmax / leaky.

// ---------------------------------------------------------------------------
// kA: blocks 0..255: 4 waves x one 64x64 adj tile each -> bm + bmT words.
//     blocks 256..303: feature transform (h, e1, e2, exp packs).
__global__ __launch_bounds__(256) void kA(
    const float* __restrict__ adj0, unsigned int* __restrict__ bm,
    unsigned int* __restrict__ bmT,
    const float* __restrict__ node, const float* __restrict__ uv,
    const float* __restrict__ Wt1, const float* __restrict__ at1,
    const float* __restrict__ Wt2, const float* __restrict__ at2,
    float* __restrict__ hcol, float* __restrict__ pack1, float* __restrict__ pack2) {
  int b = blockIdx.x;
  if (b < 256) {
    int lane = threadIdx.x & 63, w = threadIdx.x >> 6;
    int t = b * 4 + w;                  // 1024 tiles
    int ti = t >> 5, tj = t & 31;       // ti: row-block, tj: col-block
    int row = ti * 64 + lane;
    const float4* ar4 = (const float4*)(adj0 + (size_t)row * 2048 + tj * 64);
    unsigned int rowLo = 0, rowHi = 0, myLo = 0, myHi = 0;
#pragma unroll
    for (int it = 0; it < 16; ++it) {
      float4 v = ar4[it];
      unsigned long long m0 = __ballot(v.x == 1.0f);
      unsigned long long m1 = __ballot(v.y == 1.0f);
      unsigned long long m2 = __ballot(v.z == 1.0f);
      unsigned long long m3 = __ballot(v.w == 1.0f);
      int jb = it * 4;
      if (jb + 0 == lane) { myLo = (unsigned int)m0; myHi = (unsigned int)(m0 >> 32); }
      if (jb + 1 == lane) { myLo = (unsigned int)m1; myHi = (unsigned int)(m1 >> 32); }
      if (jb + 2 == lane) { myLo = (unsigned int)m2; myHi = (unsigned int)(m2 >> 32); }
      if (jb + 3 == lane) { myLo = (unsigned int)m3; myHi = (unsigned int)(m3 >> 32); }
      unsigned int rb = (v.x == 1.0f ? 1u : 0u) | (v.y == 1.0f ? 2u : 0u) |
                        (v.z == 1.0f ? 4u : 0u) | (v.w == 1.0f ? 8u : 0u);
      if (it < 8) rowLo |= rb << (it * 4);
      else rowHi |= rb << ((it - 8) * 4);
    }
    *(uint2*)&bm[(size_t)row * 64 + tj * 2] = make_uint2(rowLo, rowHi);
    int j = tj * 64 + lane;
    *(uint2*)&bmT[(size_t)j * 64 + ti * 2] = make_uint2(myLo, myHi);
    return;
  }
  __shared__ float sW[192];
  __shared__ float sA[12];
  int fb = b - 256;                 // 0..47
  int g = fb / 24;
  int h = (fb / 8) % 3;
  int e = (fb % 8) * 256 + threadIdx.x;
  const float* W = (g ? Wt2 : Wt1) + h * 192;
  const float* A = (g ? at2 : at1) + h * 12;
  const float* x = (g ? uv : node) + e * 32;
  if (threadIdx.x < 192) sW[threadIdx.x] = W[threadIdx.x];
  if (threadIdx.x < 12) sA[threadIdx.x] = A[threadIdx.x];
  __syncthreads();
  float xv[32];
#pragma unroll
  for (int i = 0; i < 32; ++i) xv[i] = x[i];
  float hv[6];
#pragma unroll
  for (int d = 0; d < 6; ++d) hv[d] = 0.f;
#pragma unroll
  for (int i = 0; i < 32; ++i)
#pragma unroll
    for (int d = 0; d < 6; ++d) hv[d] += xv[i] * sW[i * 6 + d];
  float e1 = 0.f, e2 = 0.f;
#pragma unroll
  for (int d = 0; d < 6; ++d) {
    e1 += hv[d] * sA[d];
    e2 += hv[d] * sA[6 + d];
  }
  int c = g * 3 + h;
#pragma unroll
  for (int d = 0; d < 6; ++d) hcol[(c * 6 + d) * 2048 + e] = hv[d];
  pack1[c * 2048 + e] = e1;
  pack1[(6 + c) * 2048 + e] = __expf(e1);
  pack1[(12 + c) * 2048 + e] = __expf(0.2f * e1);
  pack2[c * 2048 + e] = e2;
  pack2[(6 + c) * 2048 + e] = __expf(e2);
  pack2[(12 + c) * 2048 + e] = __expf(0.2f * e2);
}

// ---------------------------------------------------------------------------
// kB: rowsum over j -> hsS[c*6+d][i] = h[i,d]/rowsum(i,c). Block 384
// (wave = comp c), 8 rows per block, lanes sweep j 4-at-a-time.
__global__ __launch_bounds__(384) void kB(
    const unsigned int* __restrict__ bm, const float* __restrict__ pack1,
    const float* __restrict__ pack2, const float* __restrict__ hcol,
    float* __restrict__ hsS) {
  int tid = threadIdx.x;
  int c = tid >> 6, lane = tid & 63;
  int i0 = blockIdx.x * 8;
  const float4* p2_4 = (const float4*)pack2;
  float e1r[8], p1r[8], q1r[8], sum[8];
#pragma unroll
  for (int r = 0; r < 8; ++r) {
    e1r[r] = pack1[c * 2048 + i0 + r];
    p1r[r] = pack1[(6 + c) * 2048 + i0 + r];
    q1r[r] = pack1[(12 + c) * 2048 + i0 + r];
    sum[r] = 0.f;
  }
  int sh = (lane & 7) * 4;
#pragma unroll
  for (int it = 0; it < 8; ++it) {
    int j4 = it * 64 + lane;  // float4 index; covers j = 4*j4 .. +3
    float4 e2 = p2_4[c * 512 + j4];
    float4 p2 = p2_4[(6 + c) * 512 + j4];
    float4 q2 = p2_4[(12 + c) * 512 + j4];
    int wbase = it * 8 + (lane >> 3);
    float abx, aby, abz, abw;
#pragma unroll
    for (int r = 0; r < 8; ++r) {
      unsigned int wd = bm[(i0 + r) * 64 + wbase] >> sh;
      { float e = e1r[r] + e2.x; bool p = e > 0.f;
        abx = (p ? p1r[r] : q1r[r]) * (p ? p2.x : q2.x); }
      { float e = e1r[r] + e2.y; bool p = e > 0.f;
        aby = (p ? p1r[r] : q1r[r]) * (p ? p2.y : q2.y); }
      { float e = e1r[r] + e2.z; bool p = e > 0.f;
        abz = (p ? p1r[r] : q1r[r]) * (p ? p2.z : q2.z); }
      { float e = e1r[r] + e2.w; bool p = e > 0.f;
        abw = (p ? p1r[r] : q1r[r]) * (p ? p2.w : q2.w); }
      float s = ((wd & 1u) ? abx : 0.f) + ((wd & 2u) ? aby : 0.f) +
                ((wd & 4u) ? abz : 0.f) + ((wd & 8u) ? abw : 0.f);
      sum[r] += s;
    }
  }
#pragma unroll
  for (int r = 0; r < 8; ++r) {
#pragma unroll
    for (int off = 32; off > 0; off >>= 1) sum[r] += __shfl_xor(sum[r], off);
  }
  if (lane < 6) {
    int row = c * 6 + lane;
#pragma unroll
    for (int r = 0; r < 8; ++r) {
      float inv = 1.0f / sum[r];
      hsS[row * 2048 + i0 + r] = hcol[row * 2048 + i0 + r] * inv;
    }
  }
}

// ---------------------------------------------------------------------------
// kC: fused attention-aggregate + GCN1 input: for a 4-wide j-tile, full-i
// sweep (2048) of hp[j,c*6+d] = sum_i w(i,j,c)*hsS[c*6+d][i]; then elu and
// x Wg1/Wo1 -> T[j][32]. Wave = comp c; lane L owns i = s*64+L; mask words
// held in regs (wj) + broadcast via readlane. Grid 512 (j0 = blk*4).
__global__ __launch_bounds__(384) void kC(
    const unsigned int* __restrict__ bmT, const float* __restrict__ pack1,
    const float* __restrict__ pack2, const float* __restrict__ hsS,
    const float* __restrict__ Wg1, const float* __restrict__ Wo1,
    float* __restrict__ T) {
  __shared__ float sW[576];       // Wg1 (288) then Wo1 (288)
  __shared__ float sHP[4 * 37];
  int tid = threadIdx.x;
  int c = tid >> 6, L = tid & 63;
  int j0 = blockIdx.x * 4;
  if (tid < 288) { sW[tid] = Wg1[tid]; sW[288 + tid] = Wo1[tid]; }
  // per-lane mask words: wj[jj] = word L of column j0+jj (rows L*32..L*32+31)
  int wj[4];
#pragma unroll
  for (int jj = 0; jj < 4; ++jj) wj[jj] = (int)bmT[(size_t)(j0 + jj) * 64 + L];
  // wave-uniform j-side scalars
  float e2v[4], p2v[4], q2v[4];
#pragma unroll
  for (int jj = 0; jj < 4; ++jj) {
    e2v[jj] = pack2[c * 2048 + j0 + jj];
    p2v[jj] = pack2[(6 + c) * 2048 + j0 + jj];
    q2v[jj] = pack2[(12 + c) * 2048 + j0 + jj];
  }
  float acc[4][6];
#pragma unroll
  for (int jj = 0; jj < 4; ++jj)
#pragma unroll
    for (int d = 0; d < 6; ++d) acc[jj][d] = 0.f;

  for (int s = 0; s < 32; ++s) {
    int i = s * 64 + L;
    float e1 = pack1[c * 2048 + i];
    float p1 = pack1[(6 + c) * 2048 + i];
    float q1 = pack1[(12 + c) * 2048 + i];
    float h0 = hsS[(c * 6 + 0) * 2048 + i];
    float h1 = hsS[(c * 6 + 1) * 2048 + i];
    float h2 = hsS[(c * 6 + 2) * 2048 + i];
    float h3 = hsS[(c * 6 + 3) * 2048 + i];
    float h4 = hsS[(c * 6 + 4) * 2048 + i];
    float h5 = hsS[(c * 6 + 5) * 2048 + i];
#pragma unroll
    for (int jj = 0; jj < 4; ++jj) {
      int lo = __builtin_amdgcn_readlane(wj[jj], 2 * s);
      int hi = __builtin_amdgcn_readlane(wj[jj], 2 * s + 1);
      unsigned int wsel = (unsigned int)((L & 32) ? hi : lo);
      float e = e1 + e2v[jj];
      bool pos = e > 0.f;
      float ab = (pos ? p1 : q1) * (pos ? p2v[jj] : q2v[jj]);
      float wgt = ((wsel >> (L & 31)) & 1u) ? ab : 0.f;
      acc[jj][0] += wgt * h0; acc[jj][1] += wgt * h1; acc[jj][2] += wgt * h2;
      acc[jj][3] += wgt * h3; acc[jj][4] += wgt * h4; acc[jj][5] += wgt * h5;
    }
  }
  // butterfly: every lane ends with the full i-sum
#pragma unroll
  for (int jj = 0; jj < 4; ++jj)
#pragma unroll
    for (int d = 0; d < 6; ++d)
#pragma unroll
      for (int off = 32; off > 0; off >>= 1)
        acc[jj][d] += __shfl_xor(acc[jj][d], off);
  if (L == 0) {
#pragma unroll
    for (int jj = 0; jj < 4; ++jj)
#pragma unroll
      for (int d = 0; d < 6; ++d) {
        float x = acc[jj][d];
        sHP[jj * 37 + c * 6 + d] = x > 0.f ? x : __expf(x) - 1.f;  // elu
      }
  }
  __syncthreads();
  if (tid < 128) {
    int j = tid >> 5, col = tid & 31;
    int gat = col >> 4, cp = col & 15;
    const float* Wp = sW + gat * 288;
    const float* hp = sHP + j * 37 + gat * 18;
    float a = 0.f;
#pragma unroll
    for (int r = 0; r < 18; ++r) a += hp[r] * Wp[r * 16 + cp];
    T[(size_t)(j0 + j) * 32 + col] = a;
  }
}

// ---------------------------------------------------------------------------
// kD: fused GCN1-aggregate + GCN2 input: 8 rows per block, full-k sweep of
// Craw[r][col] = sum_k bit(r,k)*T[k][col] (T streamed from L2, no LDS
// staging); then relu(+bias) x Wg2/Wo2 -> T2[r][4]. Grid 256.
__global__ __launch_bounds__(256) void kD(
    const unsigned int* __restrict__ bm, const float* __restrict__ T,
    const float* __restrict__ bg1, const float* __restrict__ bo1,
    const float* __restrict__ Wg2, const float* __restrict__ Wo2,
    float* __restrict__ T2) {
  __shared__ float sC[8 * 32];
  int tid = threadIdx.x;
  int kl = tid & 31, cg = tid >> 5;   // kl: k-lane, cg: float4 col-group
  int r0 = blockIdx.x * 8;
  const float4* T4 = (const float4*)T;
  float4 acc[8];
#pragma unroll
  for (int rr = 0; rr < 8; ++rr) acc[rr] = make_float4(0.f, 0.f, 0.f, 0.f);
  for (int ch = 0; ch < 8; ++ch) {
    // prefetch 8 T values (k = ch*256 + t*32 + kl), 8-deep MLP
    float4 tv[8];
#pragma unroll
    for (int t = 0; t < 8; ++t)
      tv[t] = T4[(size_t)(ch * 256 + t * 32 + kl) * 8 + cg];
#pragma unroll
    for (int rr = 0; rr < 8; ++rr) {
      const unsigned int* wp = &bm[(size_t)(r0 + rr) * 64 + ch * 8];
      uint4 wA = *(const uint4*)wp;        // words t=0..3
      uint4 wB = *(const uint4*)(wp + 4);  // words t=4..7
      float m;
      m = (float)((wA.x >> kl) & 1u);
      acc[rr].x += m * tv[0].x; acc[rr].y += m * tv[0].y;
      acc[rr].z += m * tv[0].z; acc[rr].w += m * tv[0].w;
      m = (float)((wA.y >> kl) & 1u);
      acc[rr].x += m * tv[1].x; acc[rr].y += m * tv[1].y;
      acc[rr].z += m * tv[1].z; acc[rr].w += m * tv[1].w;
      m = (float)((wA.z >> kl) & 1u);
      acc[rr].x += m * tv[2].x; acc[rr].y += m * tv[2].y;
      acc[rr].z += m * tv[2].z; acc[rr].w += m * tv[2].w;
      m = (float)((wA.w >> kl) & 1u);
      acc[rr].x += m * tv[3].x; acc[rr].y += m * tv[3].y;
      acc[rr].z += m * tv[3].z; acc[rr].w += m * tv[3].w;
      m = (float)((wB.x >> kl) & 1u);
      acc[rr].x += m * tv[4].x; acc[rr].y += m * tv[4].y;
      acc[rr].z += m * tv[4].z; acc[rr].w += m * tv[4].w;
      m = (float)((wB.y >> kl) & 1u);
      acc[rr].x += m * tv[5].x; acc[rr].y += m * tv[5].y;
      acc[rr].z += m * tv[5].z; acc[rr].w += m * tv[5].w;
      m = (float)((wB.z >> kl) & 1u);
      acc[rr].x += m * tv[6].x; acc[rr].y += m * tv[6].y;
      acc[rr].z += m * tv[6].z; acc[rr].w += m * tv[6].w;
      m = (float)((wB.w >> kl) & 1u);
      acc[rr].x += m * tv[7].x; acc[rr].y += m * tv[7].y;
      acc[rr].z += m * tv[7].z; acc[rr].w += m * tv[7].w;
    }
  }
  // reduce over the 32 kl-lanes (stays within each 32-lane half-wave)
#pragma unroll
  for (int rr = 0; rr < 8; ++rr) {
#pragma unroll
    for (int m = 16; m > 0; m >>= 1) {
      acc[rr].x += __shfl_xor(acc[rr].x, m);
      acc[rr].y += __shfl_xor(acc[rr].y, m);
      acc[rr].z += __shfl_xor(acc[rr].z, m);
      acc[rr].w += __shfl_xor(acc[rr].w, m);
    }
  }
  if (kl == 0) {
#pragma unroll
    for (int rr = 0; rr < 8; ++rr)
      *(float4*)&sC[rr * 32 + cg * 4] = acc[rr];
  }
  __syncthreads();
  {
    int r = tid >> 5, col = tid & 31;
    int gat = col >> 4, cc = col & 15;
    float x = sC[r * 32 + col] + (gat ? bo1[cc] : bg1[cc]);
    x = x > 0.f ? x : 0.f;  // relu
    float wa = gat ? Wo2[cc * 2 + 0] : Wg2[cc * 2 + 0];
    float wb = gat ? Wo2[cc * 2 + 1] : Wg2[cc * 2 + 1];
    float pa = x * wa, pb = x * wb;
#pragma unroll
    for (int m = 8; m > 0; m >>= 1) {
      pa += __shfl_xor(pa, m);
      pb += __shfl_xor(pb, m);
    }
    if (cc == 0) {
      T2[(size_t)(r0 + r) * 4 + gat * 2 + 0] = pa;
      T2[(size_t)(r0 + r) * 4 + gat * 2 + 1] = pb;
    }
  }
}

// ---------------------------------------------------------------------------
// kE: final out = a0 @ T2 (+bias), log_softmax(axis=1) + leaky(0.01).
// Wave per row, grid 512.
__global__ __launch_bounds__(256) void kE(
    const unsigned int* __restrict__ bm, const float* __restrict__ T2,
    const float* __restrict__ bg2, const float* __restrict__ bo2,
    float* __restrict__ out) {
  int tid = threadIdx.x;
  int lane = tid & 63, w = tid >> 6;
  int r = blockIdx.x * 4 + w;
  const float4* T24 = (const float4*)T2;
  float4 acc = make_float4(0.f, 0.f, 0.f, 0.f);
  int sh = lane & 31;
#pragma unroll 8
  for (int it = 0; it < 32; ++it) {
    int k = it * 64 + lane;
    unsigned int wd = bm[r * 64 + it * 2 + (lane >> 5)];
    float m = (float)((wd >> sh) & 1u);
    float4 t = T24[k];
    acc.x += m * t.x;
    acc.y += m * t.y;
    acc.z += m * t.z;
    acc.w += m * t.w;
  }
#pragma unroll
  for (int off = 32; off > 0; off >>= 1) {
    acc.x += __shfl_down(acc.x, off);
    acc.y += __shfl_down(acc.y, off);
    acc.z += __shfl_down(acc.z, off);
    acc.w += __shfl_down(acc.w, off);
  }
  if (lane == 0) {
    float y0 = acc.x + bg2[0], y1 = acc.y + bg2[1];
    float m = fmaxf(y0, y1);
    float ls = m + logf(__expf(y0 - m) + __expf(y1 - m));
    out[r * 2 + 0] = y0 - ls;
    out[r * 2 + 1] = y1 - ls;
    float o0 = acc.z + bo2[0], o1 = acc.w + bo2[1];
    out[4096 + r * 2 + 0] = o0 > 0.f ? o0 : 0.01f * o0;
    out[4096 + r * 2 + 1] = o1 > 0.f ? o1 : 0.01f * o1;
  }
}

extern "C" void kernel_launch(void* const* d_in, const int* in_sizes, int n_in,
                              void* d_out, int out_size, void* d_ws, size_t ws_size,
                              hipStream_t stream) {
  const float* node = (const float*)d_in[0];
  const float* uv = (const float*)d_in[1];
  const float* adj = (const float*)d_in[2];  // batch 0 = first 2048*2048
  const float* Wt1 = (const float*)d_in[3];
  const float* at1 = (const float*)d_in[4];
  const float* Wt2 = (const float*)d_in[5];
  const float* at2 = (const float*)d_in[6];
  const float* Wg1 = (const float*)d_in[7];
  const float* bg1 = (const float*)d_in[8];
  const float* Wg2 = (const float*)d_in[9];
  const float* bg2 = (const float*)d_in[10];
  const float* Wo1 = (const float*)d_in[11];
  const float* bo1 = (const float*)d_in[12];
  const float* Wo2 = (const float*)d_in[13];
  const float* bo2 = (const float*)d_in[14];
  float* ws = (float*)d_ws;
  float* hcol = ws;                               // 73728
  float* pack1 = ws + 73728;                      // 36864
  float* pack2 = ws + 110592;                     // 36864
  float* hsS = ws + 147456;                       // 73728
  float* T = ws + 221184;                         // 65536
  float* T2 = ws + 286720;                        // 8192
  unsigned int* bm = (unsigned int*)(ws + 294912);   // 131072 u32 = 512 KB
  unsigned int* bmT = (unsigned int*)(ws + 425984);  // 131072 u32 = 512 KB
  float* out = (float*)d_out;

  kA<<<304, 256, 0, stream>>>(adj, bm, bmT, node, uv, Wt1, at1, Wt2, at2,
                              hcol, pack1, pack2);
  kB<<<256, 384, 0, stream>>>(bm, pack1, pack2, hcol, hsS);
  kC<<<512, 384, 0, stream>>>(bmT, pack1, pack2, hsS, Wg1, Wo1, T);
  kD<<<256, 256, 0, stream>>>(bm, T, bg1, bo1, Wg2, Wo2, T2);
  kE<<<512, 256, 0, stream>>>(bm, T2, bg2, bo2, out);
}